// Round 2
// baseline (537.463 us; speedup 1.0000x reference)
//
#include <hip/hip_runtime.h>
#include <math.h>

// N=8192 all-pairs wind-influence graph. Output: [edge_attr f32 N*N][mask01 f32 N*N]
//
// Round 4b (compile fix of round 4): __builtin_nontemporal_store needs a clang
// ext_vector_type pointer, not HIP's float4 class. Logic unchanged:
//   - Slow path (a <= ACUT = 1.9e-4): atan2(sqrt(a), sqrt(1-a)) == asin(sqrt(a))
//     = sqrt(a)*(1 + a/6 + O(a^2)), truncation error < 3e-9 rel. Replaces libm
//     atan2f (+2 sqrt) with 1 sqrt + 1 fma.
//   - dist <= 175.7 km < 300 always in the slow path -> MAX_DIST compare dead.
//   - Bearing/influence formulas BIT-IDENTICAL to the passing round-3 kernel.
//   - TI 16->32, row-loop unroll 2, non-temporal float4 stores.
// Diagonal (a==0) falls into the slow path; j!=i kills it as before.

#define NN 8192
#define TI 32      // i-rows per block
#define TJ 1024    // j-cols per block = 256 threads * 4

#define ACUT 1.9e-4f   // a > ACUT  =>  dist > 175.6 km  =>  influence < 0.26 < 0.3

typedef float floatx4 __attribute__((ext_vector_type(4)));

__global__ __launch_bounds__(256) void dyn_graph_kernel(
    const float* __restrict__ pos,     // (N,2): lat, lon (degrees)
    const float* __restrict__ wspd,
    const float* __restrict__ wdir,
    float* __restrict__ out)           // 2*N*N floats
{
    __shared__ __align__(16) float irow[TI * 12];

    const int tid   = threadIdx.x;
    const int i0    = blockIdx.y * TI;
    const int jbase = blockIdx.x * TJ + tid * 4;

    const float DEG2RAD = 0.017453292519943295f;

    // ---- stage i-side per-point values into LDS (once per block) ----
    if (tid < TI) {
        int i = i0 + tid;
        float latr = pos[2 * i]     * DEG2RAD;
        float lonr = pos[2 * i + 1] * DEG2RAD;
        float wr   = wdir[i]        * DEG2RAD;
        float s, c, hs, hc, hsl, hcl, sl, cl, swr, cwr;
        sincosf(latr,        &s,   &c);
        sincosf(0.5f * latr, &hs,  &hc);
        sincosf(0.5f * lonr, &hsl, &hcl);
        sincosf(lonr,        &sl,  &cl);
        sincosf(wr,          &swr, &cwr);
        float* p = &irow[tid * 12];
        p[0] = s;   p[1] = c;   p[2]  = hs;  p[3]  = hc;
        p[4] = hsl; p[5] = hcl; p[6]  = sl;  p[7]  = cl;
        p[8] = swr; p[9] = cwr; p[10] = wspd[i] / 10.0f;
        p[11] = 0.0f;
    }

    // ---- j-side per-point values (4 j's per thread), reused across 32 rows ----
    float4 p01 = *(const float4*)(pos + 2 * jbase);      // pos[2j .. 2j+3]
    float4 p23 = *(const float4*)(pos + 2 * jbase + 4);  // pos[2j+4 .. 2j+7]
    float jlat[4] = { p01.x, p01.z, p23.x, p23.z };
    float jlon[4] = { p01.y, p01.w, p23.y, p23.w };

    float js[4], jc[4], jhs[4], jhc[4], jhsl[4], jhcl[4], jsl[4], jcl[4];
    #pragma unroll
    for (int k = 0; k < 4; ++k) {
        float latr = jlat[k] * DEG2RAD;
        float lonr = jlon[k] * DEG2RAD;
        sincosf(latr,        &js[k],   &jc[k]);
        sincosf(0.5f * latr, &jhs[k],  &jhc[k]);
        sincosf(0.5f * lonr, &jhsl[k], &jhcl[k]);
        sincosf(lonr,        &jsl[k],  &jcl[k]);
    }

    __syncthreads();

    #pragma unroll 2
    for (int r = 0; r < TI; ++r) {
        const float4* p4 = (const float4*)&irow[r * 12];
        float4 A = p4[0], B = p4[1], C = p4[2];
        const float is  = A.x, ic  = A.y, ihs = A.z, ihc = A.w;
        const float ihsl= B.x, ihcl= B.y, isl = B.z, icl = B.w;
        const float swr = C.x, cwr = C.y, ws10= C.z;
        const int i = i0 + r;

        float ev[4], mv[4];
        #pragma unroll
        for (int k = 0; k < 4; ++k) {
            // cheap haversine 'a' via cancellation-safe half-angle products
            float shlat = jhs[k] * ihc - jhc[k] * ihs;     // sin((lat2-lat1)/2)
            float shlon = jhsl[k] * ihcl - jhcl[k] * ihsl; // sin((lon2-lon1)/2)
            float cc = ic * jc[k];
            float a = shlat * shlat + cc * (shlon * shlon);

            ev[k] = 0.0f;
            mv[k] = 0.0f;

            if (a <= ACUT) {   // ~0.7% of pairs (plus diagonal) — slow path
                float ac = fmaxf(a, 1e-12f);               // upper clamp dead (a<=1.9e-4)
                // dist = 2R*asin(sqrt(ac)); series exact to <3e-9 rel in range
                float sq = sqrtf(ac);
                float dist = 12742.0f * sq * __builtin_fmaf(ac, 0.16666667f, 1.0f);

                float sdlon = jsl[k] * icl - jcl[k] * isl;     // sin(dlon)
                float cdlon = jcl[k] * icl + jsl[k] * isl;     // cos(dlon)
                float x = sdlon * jc[k];
                float y = ic * js[k] - (is * jc[k]) * cdlon;

                float num = y * cwr + x * swr;                 // cos(atan2(x,y)-wr)*|v|
                float h2  = x * x + y * y;
                float align = num * rsqrtf(h2);

                float infl = align * ws10 * __expf(dist * -0.01f);
                // dist <= 175.7 < 300 always here: MAX_DIST test dropped
                bool m = (jbase + k != i) && (infl > 0.3f);
                ev[k] = m ? infl : 0.0f;
                mv[k] = m ? 1.0f : 0.0f;
            }
        }

        size_t idx = (size_t)i * NN + jbase;
        floatx4 evv = { ev[0], ev[1], ev[2], ev[3] };
        floatx4 mvv = { mv[0], mv[1], mv[2], mv[3] };
        __builtin_nontemporal_store(evv, (floatx4*)(out + idx));
        __builtin_nontemporal_store(mvv, (floatx4*)(out + (size_t)NN * NN + idx));
    }
}

extern "C" void kernel_launch(void* const* d_in, const int* in_sizes, int n_in,
                              void* d_out, int out_size, void* d_ws, size_t ws_size,
                              hipStream_t stream) {
    const float* pos  = (const float*)d_in[0];
    const float* wspd = (const float*)d_in[1];
    const float* wdir = (const float*)d_in[2];
    float* out = (float*)d_out;

    dim3 grid(NN / TJ, NN / TI);   // (8, 256)
    dim3 block(256);
    dyn_graph_kernel<<<grid, block, 0, stream>>>(pos, wspd, wdir, out);
}

// Round 3
// 530.991 us; speedup vs baseline: 1.0122x; 1.0122x over previous
//
#include <hip/hip_runtime.h>
#include <math.h>

// N=8192 all-pairs wind-influence graph. Output: [edge_attr f32 N*N][mask01 f32 N*N]
//
// Round 5: attack HBM write efficiency (kernel is store-bound at ~2.8 TB/s vs
// 6.2 TB/s fill ceiling; all compute-side changes in round 4 were neutral).
//   Theory: 2048 co-resident blocks x 2 output arrays = ~4096 concurrent write
//   streams of 4-KiB granules (stride 32 KiB) -> poor HBM page locality.
//   Change: 1024-thread blocks, TJ=4096 -> per-iteration block footprint is a
//   16-KiB contiguous chunk per array, 512 blocks (2/CU), 4x fewer/coarser
//   streams. Compute + numerics BIT-IDENTICAL to the passing round-4b kernel.
// Diagonal (a==0) falls into the slow path; j!=i kills it as before.

#define NN 8192
#define TI 32      // i-rows per block
#define TJ 4096    // j-cols per block = 1024 threads * 4

#define ACUT 1.9e-4f   // a > ACUT  =>  dist > 175.6 km  =>  influence < 0.26 < 0.3

typedef float floatx4 __attribute__((ext_vector_type(4)));

__global__ __launch_bounds__(1024) void dyn_graph_kernel(
    const float* __restrict__ pos,     // (N,2): lat, lon (degrees)
    const float* __restrict__ wspd,
    const float* __restrict__ wdir,
    float* __restrict__ out)           // 2*N*N floats
{
    __shared__ __align__(16) float irow[TI * 12];

    const int tid   = threadIdx.x;
    const int i0    = blockIdx.y * TI;
    const int jbase = blockIdx.x * TJ + tid * 4;

    const float DEG2RAD = 0.017453292519943295f;

    // ---- stage i-side per-point values into LDS (once per block) ----
    if (tid < TI) {
        int i = i0 + tid;
        float latr = pos[2 * i]     * DEG2RAD;
        float lonr = pos[2 * i + 1] * DEG2RAD;
        float wr   = wdir[i]        * DEG2RAD;
        float s, c, hs, hc, hsl, hcl, sl, cl, swr, cwr;
        sincosf(latr,        &s,   &c);
        sincosf(0.5f * latr, &hs,  &hc);
        sincosf(0.5f * lonr, &hsl, &hcl);
        sincosf(lonr,        &sl,  &cl);
        sincosf(wr,          &swr, &cwr);
        float* p = &irow[tid * 12];
        p[0] = s;   p[1] = c;   p[2]  = hs;  p[3]  = hc;
        p[4] = hsl; p[5] = hcl; p[6]  = sl;  p[7]  = cl;
        p[8] = swr; p[9] = cwr; p[10] = wspd[i] / 10.0f;
        p[11] = 0.0f;
    }

    // ---- j-side per-point values (4 j's per thread), reused across 32 rows ----
    float4 p01 = *(const float4*)(pos + 2 * jbase);      // pos[2j .. 2j+3]
    float4 p23 = *(const float4*)(pos + 2 * jbase + 4);  // pos[2j+4 .. 2j+7]
    float jlat[4] = { p01.x, p01.z, p23.x, p23.z };
    float jlon[4] = { p01.y, p01.w, p23.y, p23.w };

    float js[4], jc[4], jhs[4], jhc[4], jhsl[4], jhcl[4], jsl[4], jcl[4];
    #pragma unroll
    for (int k = 0; k < 4; ++k) {
        float latr = jlat[k] * DEG2RAD;
        float lonr = jlon[k] * DEG2RAD;
        sincosf(latr,        &js[k],   &jc[k]);
        sincosf(0.5f * latr, &jhs[k],  &jhc[k]);
        sincosf(0.5f * lonr, &jhsl[k], &jhcl[k]);
        sincosf(lonr,        &jsl[k],  &jcl[k]);
    }

    __syncthreads();

    #pragma unroll 2
    for (int r = 0; r < TI; ++r) {
        const float4* p4 = (const float4*)&irow[r * 12];
        float4 A = p4[0], B = p4[1], C = p4[2];
        const float is  = A.x, ic  = A.y, ihs = A.z, ihc = A.w;
        const float ihsl= B.x, ihcl= B.y, isl = B.z, icl = B.w;
        const float swr = C.x, cwr = C.y, ws10= C.z;
        const int i = i0 + r;

        float ev[4], mv[4];
        #pragma unroll
        for (int k = 0; k < 4; ++k) {
            // cheap haversine 'a' via cancellation-safe half-angle products
            float shlat = jhs[k] * ihc - jhc[k] * ihs;     // sin((lat2-lat1)/2)
            float shlon = jhsl[k] * ihcl - jhcl[k] * ihsl; // sin((lon2-lon1)/2)
            float cc = ic * jc[k];
            float a = shlat * shlat + cc * (shlon * shlon);

            ev[k] = 0.0f;
            mv[k] = 0.0f;

            if (a <= ACUT) {   // ~0.7% of pairs (plus diagonal) — slow path
                float ac = fmaxf(a, 1e-12f);               // upper clamp dead (a<=1.9e-4)
                // dist = 2R*asin(sqrt(ac)); series exact to <3e-9 rel in range
                float sq = sqrtf(ac);
                float dist = 12742.0f * sq * __builtin_fmaf(ac, 0.16666667f, 1.0f);

                float sdlon = jsl[k] * icl - jcl[k] * isl;     // sin(dlon)
                float cdlon = jcl[k] * icl + jsl[k] * isl;     // cos(dlon)
                float x = sdlon * jc[k];
                float y = ic * js[k] - (is * jc[k]) * cdlon;

                float num = y * cwr + x * swr;                 // cos(atan2(x,y)-wr)*|v|
                float h2  = x * x + y * y;
                float align = num * rsqrtf(h2);

                float infl = align * ws10 * __expf(dist * -0.01f);
                // dist <= 175.7 < 300 always here: MAX_DIST test dropped
                bool m = (jbase + k != i) && (infl > 0.3f);
                ev[k] = m ? infl : 0.0f;
                mv[k] = m ? 1.0f : 0.0f;
            }
        }

        size_t idx = (size_t)i * NN + jbase;
        floatx4 evv = { ev[0], ev[1], ev[2], ev[3] };
        floatx4 mvv = { mv[0], mv[1], mv[2], mv[3] };
        __builtin_nontemporal_store(evv, (floatx4*)(out + idx));
        __builtin_nontemporal_store(mvv, (floatx4*)(out + (size_t)NN * NN + idx));
    }
}

extern "C" void kernel_launch(void* const* d_in, const int* in_sizes, int n_in,
                              void* d_out, int out_size, void* d_ws, size_t ws_size,
                              hipStream_t stream) {
    const float* pos  = (const float*)d_in[0];
    const float* wspd = (const float*)d_in[1];
    const float* wdir = (const float*)d_in[2];
    float* out = (float*)d_out;

    dim3 grid(NN / TJ, NN / TI);   // (2, 256)
    dim3 block(1024);
    dyn_graph_kernel<<<grid, block, 0, stream>>>(pos, wspd, wdir, out);
}

// Round 4
// 529.050 us; speedup vs baseline: 1.0159x; 1.0037x over previous
//
#include <hip/hip_runtime.h>
#include <math.h>

// N=8192 all-pairs wind-influence graph. Output: [edge_attr f32 N*N][mask01 f32 N*N]
//
// Round 6: single-stream writes. Previously each wave alternated stores between
// ev (out) and mask (out + 256 MiB) every row-iteration -> two interleaved HBM
// write streams per wave. Now: phase 1 computes + stores ev rows only, packing
// the 4 mask bits/row into two 64-bit registers (32 rows x 4 bits = 128 bits);
// phase 2 (store-only, fully unrolled, static shifts) emits all mask rows.
// Each wave drives ONE contiguous write stream at a time, matching the pattern
// of the 6.2 TB/s harness fills. Numerics BIT-IDENTICAL to round 5.
// Diagonal (a==0) falls into the slow path; j!=i kills it as before.

#define NN 8192
#define TI 32      // i-rows per block
#define TJ 4096    // j-cols per block = 1024 threads * 4

#define ACUT 1.9e-4f   // a > ACUT  =>  dist > 175.6 km  =>  influence < 0.26 < 0.3

typedef float floatx4 __attribute__((ext_vector_type(4)));

__global__ __launch_bounds__(1024) void dyn_graph_kernel(
    const float* __restrict__ pos,     // (N,2): lat, lon (degrees)
    const float* __restrict__ wspd,
    const float* __restrict__ wdir,
    float* __restrict__ out)           // 2*N*N floats
{
    __shared__ __align__(16) float irow[TI * 12];

    const int tid   = threadIdx.x;
    const int i0    = blockIdx.y * TI;
    const int jbase = blockIdx.x * TJ + tid * 4;

    const float DEG2RAD = 0.017453292519943295f;

    // ---- stage i-side per-point values into LDS (once per block) ----
    if (tid < TI) {
        int i = i0 + tid;
        float latr = pos[2 * i]     * DEG2RAD;
        float lonr = pos[2 * i + 1] * DEG2RAD;
        float wr   = wdir[i]        * DEG2RAD;
        float s, c, hs, hc, hsl, hcl, sl, cl, swr, cwr;
        sincosf(latr,        &s,   &c);
        sincosf(0.5f * latr, &hs,  &hc);
        sincosf(0.5f * lonr, &hsl, &hcl);
        sincosf(lonr,        &sl,  &cl);
        sincosf(wr,          &swr, &cwr);
        float* p = &irow[tid * 12];
        p[0] = s;   p[1] = c;   p[2]  = hs;  p[3]  = hc;
        p[4] = hsl; p[5] = hcl; p[6]  = sl;  p[7]  = cl;
        p[8] = swr; p[9] = cwr; p[10] = wspd[i] / 10.0f;
        p[11] = 0.0f;
    }

    // ---- j-side per-point values (4 j's per thread), reused across 32 rows ----
    float4 p01 = *(const float4*)(pos + 2 * jbase);      // pos[2j .. 2j+3]
    float4 p23 = *(const float4*)(pos + 2 * jbase + 4);  // pos[2j+4 .. 2j+7]
    float jlat[4] = { p01.x, p01.z, p23.x, p23.z };
    float jlon[4] = { p01.y, p01.w, p23.y, p23.w };

    float js[4], jc[4], jhs[4], jhc[4], jhsl[4], jhcl[4], jsl[4], jcl[4];
    #pragma unroll
    for (int k = 0; k < 4; ++k) {
        float latr = jlat[k] * DEG2RAD;
        float lonr = jlon[k] * DEG2RAD;
        sincosf(latr,        &js[k],   &jc[k]);
        sincosf(0.5f * latr, &jhs[k],  &jhc[k]);
        sincosf(0.5f * lonr, &jhsl[k], &jhcl[k]);
        sincosf(lonr,        &jsl[k],  &jcl[k]);
    }

    __syncthreads();

    // mask bits: row r, lane-k -> bit (4*r + k); rows 0-15 in mlo, 16-31 in mhi
    unsigned long long mlo = 0ULL, mhi = 0ULL;

    // ---- phase 1: compute + ev stores (single write stream) ----
    #pragma unroll 2
    for (int r = 0; r < TI; ++r) {
        const float4* p4 = (const float4*)&irow[r * 12];
        float4 A = p4[0], B = p4[1], C = p4[2];
        const float is  = A.x, ic  = A.y, ihs = A.z, ihc = A.w;
        const float ihsl= B.x, ihcl= B.y, isl = B.z, icl = B.w;
        const float swr = C.x, cwr = C.y, ws10= C.z;
        const int i = i0 + r;

        float ev[4];
        unsigned int nib = 0u;
        #pragma unroll
        for (int k = 0; k < 4; ++k) {
            // cheap haversine 'a' via cancellation-safe half-angle products
            float shlat = jhs[k] * ihc - jhc[k] * ihs;     // sin((lat2-lat1)/2)
            float shlon = jhsl[k] * ihcl - jhcl[k] * ihsl; // sin((lon2-lon1)/2)
            float cc = ic * jc[k];
            float a = shlat * shlat + cc * (shlon * shlon);

            ev[k] = 0.0f;

            if (a <= ACUT) {   // ~0.7% of pairs (plus diagonal) — slow path
                float ac = fmaxf(a, 1e-12f);               // upper clamp dead (a<=1.9e-4)
                // dist = 2R*asin(sqrt(ac)); series exact to <3e-9 rel in range
                float sq = sqrtf(ac);
                float dist = 12742.0f * sq * __builtin_fmaf(ac, 0.16666667f, 1.0f);

                float sdlon = jsl[k] * icl - jcl[k] * isl;     // sin(dlon)
                float cdlon = jcl[k] * icl + jsl[k] * isl;     // cos(dlon)
                float x = sdlon * jc[k];
                float y = ic * js[k] - (is * jc[k]) * cdlon;

                float num = y * cwr + x * swr;                 // cos(atan2(x,y)-wr)*|v|
                float h2  = x * x + y * y;
                float align = num * rsqrtf(h2);

                float infl = align * ws10 * __expf(dist * -0.01f);
                // dist <= 175.7 < 300 always here: MAX_DIST test dropped
                bool m = (jbase + k != i) && (infl > 0.3f);
                ev[k] = m ? infl : 0.0f;
                nib |= (m ? 1u : 0u) << k;
            }
        }

        // accumulate mask nibble (defined shifts: amount always < 64)
        unsigned long long val = (unsigned long long)nib << ((4 * r) & 63);
        mlo |= (r < 16) ? val : 0ULL;
        mhi |= (r < 16) ? 0ULL : val;

        size_t idx = (size_t)i * NN + jbase;
        floatx4 evv = { ev[0], ev[1], ev[2], ev[3] };
        __builtin_nontemporal_store(evv, (floatx4*)(out + idx));
    }

    // ---- phase 2: mask stores only (single write stream) ----
    float* outm = out + (size_t)NN * NN;
    #pragma unroll
    for (int r = 0; r < TI; ++r) {
        unsigned int nib = (unsigned int)(((r < 16 ? mlo : mhi) >> (4 * (r & 15))) & 0xFULL);
        floatx4 mvv = { (float)(nib & 1u), (float)((nib >> 1) & 1u),
                        (float)((nib >> 2) & 1u), (float)((nib >> 3) & 1u) };
        size_t idx = (size_t)(i0 + r) * NN + jbase;
        __builtin_nontemporal_store(mvv, (floatx4*)(outm + idx));
    }
}

extern "C" void kernel_launch(void* const* d_in, const int* in_sizes, int n_in,
                              void* d_out, int out_size, void* d_ws, size_t ws_size,
                              hipStream_t stream) {
    const float* pos  = (const float*)d_in[0];
    const float* wspd = (const float*)d_in[1];
    const float* wdir = (const float*)d_in[2];
    float* out = (float*)d_out;

    dim3 grid(NN / TJ, NN / TI);   // (2, 256)
    dim3 block(1024);
    dyn_graph_kernel<<<grid, block, 0, stream>>>(pos, wspd, wdir, out);
}